// Round 5
// baseline (1378.622 us; speedup 1.0000x reference)
//
#include <hip/hip_runtime.h>
#include <math.h>

#define NB 8192
#define BATCH 2
#define KNN 20
#define BN (BATCH*NB)
#define NE (BN*KNN)        // 327680 edges
#define GT 16              // tiles per staged group (16 KB)
#define NG 8               // groups per pass
#define FIXG 512           // fixup grid
#define BIG 3.0e38f

__device__ __forceinline__ float gelu_f(float x){
    float x3 = x*x*x;
    float a = 0.7978845608028654f*(x + 0.044715f*x3);
    float e2 = __expf(2.0f*a);
    float th = 1.0f - __fdividef(2.0f, e2+1.0f);
    return 0.5f*x*(1.0f+th);
}

__device__ __forceinline__ float wave_sum(float v){
    #pragma unroll
    for (int s=1;s<64;s<<=1) v += __shfl_xor(v, s);
    return v;
}
__device__ __forceinline__ float wave_max(float v){
    #pragma unroll
    for (int s=1;s<64;s<<=1) v = fmaxf(v, __shfl_xor(v, s));
    return v;
}

// ---------------- prep: pos4 {x,y,z,r2}, vel4 {vx,vy,vz,massf}; zero suspect cnt ----------------
__global__ __launch_bounds__(256) void prep_kernel(const float* __restrict__ z,
                                                   float4* __restrict__ pos4,
                                                   float4* __restrict__ vel4,
                                                   int* __restrict__ sus_cnt){
    int g = blockIdx.x*256 + threadIdx.x;
    if (g == 0) sus_cnt[0] = 0;
    if (g >= BN) return;
    const float* zp = z + (size_t)g*7;
    float x = zp[0], y = zp[1], zz = zp[2];
    float r2 = x*x + y*y + zz*zz;
    pos4[g] = make_float4(x, y, zz, r2);
    vel4[g] = make_float4(zp[3], zp[4], zp[5], zp[6]);
}

// ---------------- cond MLP + collapsed constants + packed edge weights ----------------
// consts floats: C[2][128]@0, S1[128]@256, S2[128]@384, D[2][64]@512, T1[64]@640
// pack: per h (128): {C0,C1,S1,S2, W72,W73,W74,W75, V0,V1,V2,V3} = 12 floats = 3 float4
__global__ __launch_bounds__(256) void cond_kernel(const float* __restrict__ t,
        const float* __restrict__ conditioning,
        const float* __restrict__ Wc1, const float* __restrict__ bc1,
        const float* __restrict__ Wc2, const float* __restrict__ bc2,
        const float* __restrict__ Wc3, const float* __restrict__ bc3,
        const float* __restrict__ We1, const float* __restrict__ be1,
        const float* __restrict__ We2,
        const float* __restrict__ Wn1, const float* __restrict__ bn1,
        float* __restrict__ consts, float* __restrict__ pack){
    int b = blockIdx.x;
    int tid = threadIdx.x;
    __shared__ float ci[36];
    __shared__ float h1[144];
    __shared__ float h2[144];
    __shared__ float cnd[36];
    float tv = t[b];
    if (tid < 16){
        float f = expf(-9.210340371976184f * (float)tid / 15.0f);
        float a = tv*f;
        ci[tid]    = sinf(a);
        ci[16+tid] = cosf(a);
    }
    if (tid < 4) ci[32+tid] = conditioning[b*4+tid];
    __syncthreads();
    if (tid < 144){
        float acc = bc1[tid];
        #pragma unroll
        for (int c=0;c<36;c++) acc += ci[c]*Wc1[c*144+tid];
        h1[tid] = gelu_f(acc);
    }
    __syncthreads();
    if (tid < 144){
        float acc = bc2[tid];
        #pragma unroll 36
        for (int c=0;c<144;c++) acc += h1[c]*Wc2[c*144+tid];
        h2[tid] = gelu_f(acc);
    }
    __syncthreads();
    if (tid < 36){
        float acc = bc3[tid];
        #pragma unroll 36
        for (int c=0;c<144;c++) acc += h2[c]*Wc3[c*36+tid];
        cnd[tid] = acc;
    }
    __syncthreads();
    if (tid < 128){
        float accC = be1[tid], s1 = 0.f, s2 = 0.f;
        #pragma unroll
        for (int c=0;c<36;c++){
            float w1 = We1[c*128+tid];
            float w2 = We1[(36+c)*128+tid];
            accC += cnd[c]*(w1+w2);
            s1 += w1; s2 += w2;
        }
        consts[b*128+tid] = accC;
        pack[tid*12 + b] = accC;
        if (b==0){
            consts[256+tid] = s1; consts[384+tid] = s2;
            pack[tid*12+2] = s1;
            pack[tid*12+3] = s2;
            pack[tid*12+4] = We1[72*128+tid];
            pack[tid*12+5] = We1[73*128+tid];
            pack[tid*12+6] = We1[74*128+tid];
            pack[tid*12+7] = We1[75*128+tid];
            pack[tid*12+8]  = We2[tid*4+0];
            pack[tid*12+9]  = We2[tid*4+1];
            pack[tid*12+10] = We2[tid*4+2];
            pack[tid*12+11] = We2[tid*4+3];
        }
    }
    if (tid < 64){
        float accD = bn1[tid], t1 = 0.f;
        #pragma unroll
        for (int c=0;c<36;c++){
            float w = Wn1[c*64+tid];
            accD += cnd[c]*w;
            t1 += w;
        }
        consts[512 + b*64 + tid] = accD;
        if (b==0) consts[640+tid] = t1;
    }
}

// ---------------- KNN: single LDS-staged scan, per-lane top-4, compact+sort, suspect fixup ----------------
__global__ __launch_bounds__(512, 4) void knn_kernel(const float4* __restrict__ pos4,
                                                     int* __restrict__ nbr,
                                                     int* __restrict__ sus_cnt,
                                                     int* __restrict__ sus_id){
    __shared__ float4 sPos[GT*64];      // 16 KB
    __shared__ float2 sC[8*64];         // per-wave compact buffers, 4 KB
    int tid = threadIdx.x;
    int w = tid >> 6, lane = tid & 63;
    int n0g = blockIdx.x * 32;
    int b = n0g >> 13;
    int n0 = n0g & (NB-1);
    const float4* __restrict__ P = pos4 + b*NB;

    float nx[4], ny[4], nz[4], pw[4];
    float bd[4][4]; int bi[4][4];
    #pragma unroll
    for (int k=0;k<4;k++){
        float4 p = P[n0 + w*4 + k];
        nx[k] = -2.0f*p.x; ny[k] = -2.0f*p.y; nz[k] = -2.0f*p.z; pw[k] = p.w;
        #pragma unroll
        for (int r=0;r<4;r++){ bd[k][r] = BIG; bi[k][r] = 0x7fffffff; }
    }
    int selfTile = n0 >> 6;            // all 32 block nodes share one tile (n0 is 32-aligned)
    int sl0 = (n0 & 63) + w*4;         // self lane for node k is sl0+k

    // ---- single scan with per-lane sorted top-4 ----
    float4 pre0 = P[(w*2    )*64 + lane];
    float4 pre1 = P[(w*2 + 1)*64 + lane];
    for (int g=0; g<NG; ++g){
        __syncthreads();
        sPos[(w*2    )*64 + lane] = pre0;
        sPos[(w*2 + 1)*64 + lane] = pre1;
        if (g+1 < NG){
            pre0 = P[((g+1)*GT + w*2    )*64 + lane];
            pre1 = P[((g+1)*GT + w*2 + 1)*64 + lane];
        }
        __syncthreads();
        #pragma unroll 4
        for (int t=0;t<GT;t++){
            int gt = g*GT + t;
            float4 q = sPos[t*64 + lane];
            int j = (gt<<6) + lane;
            if (gt != selfTile){
                #pragma unroll
                for (int k=0;k<4;k++){
                    float d2 = fmaf(nx[k],q.x, fmaf(ny[k],q.y, fmaf(nz[k],q.z, pw[k]+q.w)));
                    unsigned long long need = __ballot(d2 < bd[k][3]);
                    if (need){
                        float vd = d2; int vi = j;
                        #pragma unroll
                        for (int s=0;s<4;s++){
                            bool c = vd < bd[k][s];
                            float td = bd[k][s]; int ti = bi[k][s];
                            bd[k][s] = c ? vd : td;  bi[k][s] = c ? vi : ti;
                            vd       = c ? td : vd;  vi       = c ? ti : vi;
                        }
                    }
                }
            } else {
                #pragma unroll
                for (int k=0;k<4;k++){
                    float d2 = fmaf(nx[k],q.x, fmaf(ny[k],q.y, fmaf(nz[k],q.z, pw[k]+q.w)));
                    if (lane == sl0 + k) d2 = BIG;
                    unsigned long long need = __ballot(d2 < bd[k][3]);
                    if (need){
                        float vd = d2; int vi = j;
                        #pragma unroll
                        for (int s=0;s<4;s++){
                            bool c = vd < bd[k][s];
                            float td = bd[k][s]; int ti = bi[k][s];
                            bd[k][s] = c ? vd : td;  bi[k][s] = c ? vi : ti;
                            vd       = c ? td : vd;  vi       = c ? ti : vi;
                        }
                    }
                }
            }
        }
    }

    unsigned long long lt = (1ull << lane) - 1ull;
    // ---- per node: T -> compact -> lex sort -> top-20 + suspect check ----
    #pragma unroll 1
    for (int k=0;k<4;k++){
        int node = n0g + w*4 + k;
        // T = 20th smallest of lane minima (exact upper bound on d20)
        float v = bd[k][0];
        #pragma unroll
        for (int K=2; K<=64; K<<=1){
            #pragma unroll
            for (int j=K>>1; j>0; j>>=1){
                float o = __shfl_xor(v, j);
                bool keepmin = (((lane & j) == 0) == ((lane & K) == 0));
                float mn = fminf(v,o), mx = fmaxf(v,o);
                v = keepmin ? mn : mx;
            }
        }
        float T = __shfl(v, 19);

        // compact retained values <= T into this wave's LDS buffer
        int cnt = 0;
        #pragma unroll
        for (int r=0;r<4;r++){
            bool take = (bd[k][r] <= T);
            unsigned long long m = __ballot(take);
            if (take){
                int off = cnt + (int)__popcll(m & lt);
                if (off < 64) sC[w*64 + off] = make_float2(bd[k][r], __int_as_float(bi[k][r]));
            }
            cnt += (int)__popcll(m);
        }
        int mm = cnt > 64 ? 64 : cnt;

        // lex bitonic-64 over compacted candidates
        float d; int idx;
        if (lane < mm){
            float2 e = sC[w*64 + lane];
            d = e.x; idx = __float_as_int(e.y);
        } else { d = BIG; idx = 0x7f000000 + lane; }
        #pragma unroll
        for (int K=2; K<=64; K<<=1){
            #pragma unroll
            for (int j=K>>1; j>0; j>>=1){
                float od = __shfl_xor(d, j);
                int   oi = __shfl_xor(idx, j);
                bool pless = (od < d) || (od == d && oi < idx);
                bool keepmin = (((lane & j) == 0) == ((lane & K) == 0));
                if (pless == keepmin){ d = od; idx = oi; }
            }
        }
        float T20 = __shfl(d, 19);

        // suspect: some lane's discards (all >= bd[k][3]) could rank within top-20
        bool susp = (bd[k][3] <= T20) || (cnt > 64);
        unsigned long long sm = __ballot(susp);
        if (sm){
            if (lane == 0){
                int slot = atomicAdd(sus_cnt, 1);
                sus_id[slot] = node;
            }
        }
        if (lane < KNN) nbr[(size_t)node*KNN + lane] = idx;
    }
}

// ---------------- fixup: exact top-8/lane + pop-merge for suspect nodes (R1-proven) ----------------
__global__ __launch_bounds__(64) void fixup_kernel(const float4* __restrict__ pos4,
                                                   const int* __restrict__ sus_cnt,
                                                   const int* __restrict__ sus_id,
                                                   int* __restrict__ nbr){
    int lane = threadIdx.x;
    int nsus = sus_cnt[0];
    for (int s = blockIdx.x; s < nsus; s += FIXG){
        int node = sus_id[s];
        int b = node >> 13;
        int i = node & (NB-1);
        const float4* __restrict__ P = pos4 + b*NB;
        float4 pi = P[i];
        float pwv = pi.w;
        float n2x = -2.0f*pi.x, n2y = -2.0f*pi.y, n2z = -2.0f*pi.z;

        float bd[8]; int bi8[8];
        #pragma unroll
        for (int r=0;r<8;r++){ bd[r] = BIG; bi8[r] = 0x7fffffff; }
        for (int tk=0; tk<128; ++tk){
            int j = (tk<<6) + lane;
            float4 q = P[j];
            float d2 = fmaf(n2x,q.x, fmaf(n2y,q.y, fmaf(n2z,q.z, pwv+q.w)));
            if (j == i) d2 = BIG;
            if (d2 < bd[7]){
                float vd = d2; int vi = j;
                #pragma unroll
                for (int r=0;r<8;r++){
                    bool c = vd < bd[r];
                    float td = bd[r]; int ti = bi8[r];
                    bd[r] = c ? vd : td;  bi8[r] = c ? vi : ti;
                    vd    = c ? td : vd;  vi    = c ? ti : vi;
                }
            }
        }
        int* outp = nbr + (size_t)node*KNN;
        for (int r=0; r<KNN; r++){
            float d = bd[0]; int ii = bi8[0];
            #pragma unroll
            for (int st=1; st<64; st<<=1){
                float od = __shfl_xor(d, st);
                int   oi = __shfl_xor(ii, st);
                if (od < d || (od == d && oi < ii)){ d = od; ii = oi; }
            }
            if (lane == 0) outp[r] = ii;
            if (bd[0] == d && bi8[0] == ii){
                #pragma unroll
                for (int st=0;st<7;st++){ bd[st]=bd[st+1]; bi8[st]=bi8[st+1]; }
                bd[7] = BIG; bi8[7] = 0x7fffffff;
            }
        }
    }
}

// ---------------- edge MLP (collapsed), 2 edges/thread, LDS weights ----------------
// ebuf: logit[NE], smsg[NE], ux[NE], uy[NE], uz[NE]
__global__ __launch_bounds__(256) void edge_kernel(const float4* __restrict__ pos4,
        const float4* __restrict__ vel4,
        const int* __restrict__ nbr,
        const float* __restrict__ pack,
        const float* __restrict__ be2,
        float* __restrict__ ebuf){
    __shared__ float4 sP[384];   // 6 KB: 3 float4 per h
    int tid = threadIdx.x;
    #pragma unroll
    for (int k=tid; k<384; k+=256) sP[k] = ((const float4*)pack)[k];
    __syncthreads();

    bool bb = (blockIdx.x >= 320);     // NE/2 = 163840 = 320*512, block-uniform batch
    int e1 = blockIdx.x*512 + tid;
    int e2 = e1 + 256;

    int i1 = e1 / KNN;
    int i2 = e2 / KNN;
    int base1 = (i1 >> 13)*NB;
    int base2 = (i2 >> 13)*NB;
    int s1 = nbr[e1], s2 = nbr[e2];
    float4 ps1 = pos4[base1 + s1], pt1 = pos4[i1];
    float4 vs1 = vel4[base1 + s1], vt1 = vel4[i1];
    float4 ps2 = pos4[base2 + s2], pt2 = pos4[i2];
    float4 vs2 = vel4[base2 + s2], vt2 = vel4[i2];

    float rx1 = ps1.x-pt1.x, ry1 = ps1.y-pt1.y, rz1 = ps1.z-pt1.z;
    float r21 = rx1*rx1 + ry1*ry1 + rz1*rz1;
    float vv1 = vs1.x*vt1.x + vs1.y*vt1.y + vs1.z*vt1.z;
    float vsr1= vs1.x*rx1 + vs1.y*ry1 + vs1.z*rz1;
    float vtr1= vt1.x*rx1 + vt1.y*ry1 + vt1.z*rz1;
    float mfs1= vs1.w, mft1 = vt1.w;

    float rx2 = ps2.x-pt2.x, ry2 = ps2.y-pt2.y, rz2 = ps2.z-pt2.z;
    float r22 = rx2*rx2 + ry2*ry2 + rz2*rz2;
    float vv2 = vs2.x*vt2.x + vs2.y*vt2.y + vs2.z*vt2.z;
    float vsr2= vs2.x*rx2 + vs2.y*ry2 + vs2.z*rz2;
    float vtr2= vt2.x*rx2 + vt2.y*ry2 + vt2.z*rz2;
    float mfs2= vs2.w, mft2 = vt2.w;

    float a0 = be2[0], a1 = be2[1], a2 = be2[2], a3 = be2[3];
    float b0 = a0, b1 = a1, b2 = a2, b3 = a3;
    #pragma unroll 4
    for (int h=0; h<128; h++){
        float4 A  = sP[h*3];
        float4 Bv = sP[h*3+1];
        float4 C  = sP[h*3+2];
        float base = bb ? A.y : A.x;
        float x1 = base + mfs1*A.z + mft1*A.w + r21*Bv.x + vv1*Bv.y + vsr1*Bv.z + vtr1*Bv.w;
        float x2 = base + mfs2*A.z + mft2*A.w + r22*Bv.x + vv2*Bv.y + vsr2*Bv.z + vtr2*Bv.w;
        float g1 = gelu_f(x1);
        float g2 = gelu_f(x2);
        a0 += g1*C.x; a1 += g1*C.y; a2 += g1*C.z; a3 += g1*C.w;
        b0 += g2*C.x; b1 += g2*C.y; b2 += g2*C.z; b3 += g2*C.w;
    }
    ebuf[e1]        = a0;
    ebuf[NE + e1]   = a1;
    ebuf[2*NE + e1] = a2*rx1 + a3*vs1.x;
    ebuf[3*NE + e1] = a2*ry1 + a3*vs1.y;
    ebuf[4*NE + e1] = a2*rz1 + a3*vs1.z;
    ebuf[e2]        = b0;
    ebuf[NE + e2]   = b1;
    ebuf[2*NE + e2] = b2*rx2 + b3*vs2.x;
    ebuf[3*NE + e2] = b2*ry2 + b3*vs2.y;
    ebuf[4*NE + e2] = b2*rz2 + b3*vs2.z;
}

// ---------------- node: softmax + aggregate + node MLP + output, wave per node ----------------
__global__ __launch_bounds__(256) void node_kernel(const float* __restrict__ z,
        const float4* __restrict__ vel4,
        const float* __restrict__ consts,
        const float* __restrict__ Wn1,
        const float* __restrict__ Wn2,
        const float* __restrict__ bn2,
        const float* __restrict__ alpha_p,
        const float* __restrict__ beta_p,
        const float* __restrict__ ebuf,
        float* __restrict__ out){
    int g = blockIdx.x*4 + (threadIdx.x>>6);
    int lane = threadIdx.x & 63;
    int b = g >> 13;

    float lg = -BIG, sm = 0.f, ux = 0.f, uy = 0.f, uz = 0.f;
    if (lane < KNN){
        size_t e = (size_t)g*KNN + lane;
        lg = ebuf[e]; sm = ebuf[NE+e]; ux = ebuf[2*NE+e]; uy = ebuf[3*NE+e]; uz = ebuf[4*NE+e];
    }
    float mx = wave_max(lg);
    float a = (lane < KNN) ? __expf(lg - mx) : 0.0f;
    float denom = wave_sum(a);
    float wv = a / denom;
    float sagg = wave_sum(wv*sm);
    float vax  = wave_sum(wv*ux);
    float vay  = wave_sum(wv*uy);
    float vaz  = wave_sum(wv*uz);

    float mf = vel4[g].w;
    float x = consts[512 + b*64 + lane] + mf*consts[640+lane] + sagg*Wn1[36*64+lane];
    float y = gelu_f(x)*Wn2[lane];
    float sout = wave_sum(y) + bn2[0];

    if (lane < 7){
        float alpha = alpha_p[0], beta = beta_p[0];
        float zl = z[(size_t)g*7 + lane];
        float r;
        if      (lane==0) r = zl + alpha*vax;
        else if (lane==1) r = zl + alpha*vay;
        else if (lane==2) r = zl + alpha*vaz;
        else if (lane==3) r = beta*vax;
        else if (lane==4) r = beta*vay;
        else if (lane==5) r = beta*vaz;
        else              r = sout;
        out[(size_t)g*7 + lane] = zl + r;
    }
}

extern "C" void kernel_launch(void* const* d_in, const int* in_sizes, int n_in,
                              void* d_out, int out_size, void* d_ws, size_t ws_size,
                              hipStream_t stream) {
    const float* z    = (const float*)d_in[0];
    const float* t    = (const float*)d_in[1];
    const float* cond = (const float*)d_in[2];
    const float* Wc1  = (const float*)d_in[4];
    const float* bc1  = (const float*)d_in[5];
    const float* Wc2  = (const float*)d_in[6];
    const float* bc2  = (const float*)d_in[7];
    const float* Wc3  = (const float*)d_in[8];
    const float* bc3  = (const float*)d_in[9];
    const float* We1  = (const float*)d_in[10];
    const float* be1  = (const float*)d_in[11];
    const float* We2  = (const float*)d_in[12];
    const float* be2  = (const float*)d_in[13];
    const float* Wn1  = (const float*)d_in[14];
    const float* bn1  = (const float*)d_in[15];
    const float* Wn2  = (const float*)d_in[16];
    const float* bn2  = (const float*)d_in[17];
    const float* alp  = (const float*)d_in[18];
    const float* bet  = (const float*)d_in[19];
    float* out = (float*)d_out;

    char* ws = (char*)d_ws;
    float4* pos4   = (float4*)(ws);                      // 262144 B
    float4* vel4   = (float4*)(ws + 262144);             // 262144 B
    float*  consts = (float*)(ws + 524288);              // 4096 B
    float*  pack   = (float*)(ws + 528384);              // 6144 B
    int*    nbr    = (int*)(ws + 534528);                // 1310720 B
    int*    sus_c  = (int*)(ws + 1845248);               // 256 B
    int*    sus_id = (int*)(ws + 1845504);               // 65536 B
    float*  ebuf   = (float*)(ws + 1911040);             // 6553600 B

    prep_kernel<<<dim3(BN/256), dim3(256), 0, stream>>>(z, pos4, vel4, sus_c);
    cond_kernel<<<dim3(BATCH), dim3(256), 0, stream>>>(t, cond, Wc1, bc1, Wc2, bc2,
                                                       Wc3, bc3, We1, be1, We2, Wn1, bn1,
                                                       consts, pack);
    knn_kernel<<<dim3(BN/32), dim3(512), 0, stream>>>(pos4, nbr, sus_c, sus_id);
    fixup_kernel<<<dim3(FIXG), dim3(64), 0, stream>>>(pos4, sus_c, sus_id, nbr);
    edge_kernel<<<dim3(NE/512), dim3(256), 0, stream>>>(pos4, vel4, nbr, pack, be2, ebuf);
    node_kernel<<<dim3(BN/4), dim3(256), 0, stream>>>(z, vel4, consts, Wn1, Wn2, bn2,
                                                      alp, bet, ebuf, out);
}

// Round 6
// 303.562 us; speedup vs baseline: 4.5415x; 4.5415x over previous
//
#include <hip/hip_runtime.h>
#include <math.h>

#define NB 8192
#define BATCH 2
#define KNN 20
#define BN (BATCH*NB)
#define NE (BN*KNN)        // 327680 edges
#define GT 16              // tiles per staged group (16 KB)
#define NG 8               // groups per pass
#define FIXG 512           // fixup grid
#define BIG 3.0e38f

__device__ __forceinline__ float gelu_f(float x){
    float x3 = x*x*x;
    float a = 0.7978845608028654f*(x + 0.044715f*x3);
    float e2 = __expf(2.0f*a);
    float th = 1.0f - __fdividef(2.0f, e2+1.0f);
    return 0.5f*x*(1.0f+th);
}

__device__ __forceinline__ float wave_sum(float v){
    #pragma unroll
    for (int s=1;s<64;s<<=1) v += __shfl_xor(v, s);
    return v;
}
__device__ __forceinline__ float wave_max(float v){
    #pragma unroll
    for (int s=1;s<64;s<<=1) v = fmaxf(v, __shfl_xor(v, s));
    return v;
}

// ---------------- prep: pos4 {x,y,z,r2}, vel4 {vx,vy,vz,massf}; zero suspect cnt ----------------
__global__ __launch_bounds__(256) void prep_kernel(const float* __restrict__ z,
                                                   float4* __restrict__ pos4,
                                                   float4* __restrict__ vel4,
                                                   int* __restrict__ sus_cnt){
    int g = blockIdx.x*256 + threadIdx.x;
    if (g == 0) sus_cnt[0] = 0;
    if (g >= BN) return;
    const float* zp = z + (size_t)g*7;
    float x = zp[0], y = zp[1], zz = zp[2];
    float r2 = x*x + y*y + zz*zz;
    pos4[g] = make_float4(x, y, zz, r2);
    vel4[g] = make_float4(zp[3], zp[4], zp[5], zp[6]);
}

// ---------------- cond MLP + collapsed constants + packed edge weights ----------------
// consts floats: C[2][128]@0, S1[128]@256, S2[128]@384, D[2][64]@512, T1[64]@640
// pack: per h (128): {C0,C1,S1,S2, W72,W73,W74,W75, V0,V1,V2,V3} = 12 floats = 3 float4
__global__ __launch_bounds__(256) void cond_kernel(const float* __restrict__ t,
        const float* __restrict__ conditioning,
        const float* __restrict__ Wc1, const float* __restrict__ bc1,
        const float* __restrict__ Wc2, const float* __restrict__ bc2,
        const float* __restrict__ Wc3, const float* __restrict__ bc3,
        const float* __restrict__ We1, const float* __restrict__ be1,
        const float* __restrict__ We2,
        const float* __restrict__ Wn1, const float* __restrict__ bn1,
        float* __restrict__ consts, float* __restrict__ pack){
    int b = blockIdx.x;
    int tid = threadIdx.x;
    __shared__ float ci[36];
    __shared__ float h1[144];
    __shared__ float h2[144];
    __shared__ float cnd[36];
    float tv = t[b];
    if (tid < 16){
        float f = expf(-9.210340371976184f * (float)tid / 15.0f);
        float a = tv*f;
        ci[tid]    = sinf(a);
        ci[16+tid] = cosf(a);
    }
    if (tid < 4) ci[32+tid] = conditioning[b*4+tid];
    __syncthreads();
    if (tid < 144){
        float acc = bc1[tid];
        #pragma unroll
        for (int c=0;c<36;c++) acc += ci[c]*Wc1[c*144+tid];
        h1[tid] = gelu_f(acc);
    }
    __syncthreads();
    if (tid < 144){
        float acc = bc2[tid];
        #pragma unroll 36
        for (int c=0;c<144;c++) acc += h1[c]*Wc2[c*144+tid];
        h2[tid] = gelu_f(acc);
    }
    __syncthreads();
    if (tid < 36){
        float acc = bc3[tid];
        #pragma unroll 36
        for (int c=0;c<144;c++) acc += h2[c]*Wc3[c*36+tid];
        cnd[tid] = acc;
    }
    __syncthreads();
    if (tid < 128){
        float accC = be1[tid], s1 = 0.f, s2 = 0.f;
        #pragma unroll
        for (int c=0;c<36;c++){
            float w1 = We1[c*128+tid];
            float w2 = We1[(36+c)*128+tid];
            accC += cnd[c]*(w1+w2);
            s1 += w1; s2 += w2;
        }
        consts[b*128+tid] = accC;
        pack[tid*12 + b] = accC;
        if (b==0){
            consts[256+tid] = s1; consts[384+tid] = s2;
            pack[tid*12+2] = s1;
            pack[tid*12+3] = s2;
            pack[tid*12+4] = We1[72*128+tid];
            pack[tid*12+5] = We1[73*128+tid];
            pack[tid*12+6] = We1[74*128+tid];
            pack[tid*12+7] = We1[75*128+tid];
            pack[tid*12+8]  = We2[tid*4+0];
            pack[tid*12+9]  = We2[tid*4+1];
            pack[tid*12+10] = We2[tid*4+2];
            pack[tid*12+11] = We2[tid*4+3];
        }
    }
    if (tid < 64){
        float accD = bn1[tid], t1 = 0.f;
        #pragma unroll
        for (int c=0;c<36;c++){
            float w = Wn1[c*64+tid];
            accD += cnd[c]*w;
            t1 += w;
        }
        consts[512 + b*64 + tid] = accD;
        if (b==0) consts[640+tid] = t1;
    }
}

// ---------------- KNN: single LDS-staged scan, per-lane top-4, compact+sort, suspect fixup ----------------
__global__ __launch_bounds__(512, 4) void knn_kernel(const float4* __restrict__ pos4,
                                                     int* __restrict__ nbr,
                                                     int* __restrict__ sus_cnt,
                                                     int* __restrict__ sus_id){
    __shared__ float4 sPos[GT*64];      // 16 KB
    __shared__ float2 sC[8*64];         // per-wave compact buffers, 4 KB
    int tid = threadIdx.x;
    int w = tid >> 6, lane = tid & 63;
    int n0g = blockIdx.x * 32;
    int b = n0g >> 13;
    int n0 = n0g & (NB-1);
    const float4* __restrict__ P = pos4 + b*NB;

    float nx[4], ny[4], nz[4], pw[4];
    float bd[4][4]; int bi[4][4];
    #pragma unroll
    for (int k=0;k<4;k++){
        float4 p = P[n0 + w*4 + k];
        nx[k] = -2.0f*p.x; ny[k] = -2.0f*p.y; nz[k] = -2.0f*p.z; pw[k] = p.w;
        #pragma unroll
        for (int r=0;r<4;r++){ bd[k][r] = BIG; bi[k][r] = 0x7fffffff; }
    }
    int selfTile = n0 >> 6;            // all 32 block nodes share one tile (n0 is 32-aligned)
    int sl0 = (n0 & 63) + w*4;         // self lane for node k is sl0+k

    // ---- single scan with per-lane sorted top-4 ----
    float4 pre0 = P[(w*2    )*64 + lane];
    float4 pre1 = P[(w*2 + 1)*64 + lane];
    for (int g=0; g<NG; ++g){
        __syncthreads();
        sPos[(w*2    )*64 + lane] = pre0;
        sPos[(w*2 + 1)*64 + lane] = pre1;
        if (g+1 < NG){
            pre0 = P[((g+1)*GT + w*2    )*64 + lane];
            pre1 = P[((g+1)*GT + w*2 + 1)*64 + lane];
        }
        __syncthreads();
        #pragma unroll 4
        for (int t=0;t<GT;t++){
            int gt = g*GT + t;
            float4 q = sPos[t*64 + lane];
            int j = (gt<<6) + lane;
            if (gt != selfTile){
                #pragma unroll
                for (int k=0;k<4;k++){
                    float d2 = fmaf(nx[k],q.x, fmaf(ny[k],q.y, fmaf(nz[k],q.z, pw[k]+q.w)));
                    unsigned long long need = __ballot(d2 < bd[k][3]);
                    if (need){
                        float vd = d2; int vi = j;
                        #pragma unroll
                        for (int s=0;s<4;s++){
                            bool c = vd < bd[k][s];
                            float td = bd[k][s]; int ti = bi[k][s];
                            bd[k][s] = c ? vd : td;  bi[k][s] = c ? vi : ti;
                            vd       = c ? td : vd;  vi       = c ? ti : vi;
                        }
                    }
                }
            } else {
                #pragma unroll
                for (int k=0;k<4;k++){
                    float d2 = fmaf(nx[k],q.x, fmaf(ny[k],q.y, fmaf(nz[k],q.z, pw[k]+q.w)));
                    if (lane == sl0 + k) d2 = BIG;
                    unsigned long long need = __ballot(d2 < bd[k][3]);
                    if (need){
                        float vd = d2; int vi = j;
                        #pragma unroll
                        for (int s=0;s<4;s++){
                            bool c = vd < bd[k][s];
                            float td = bd[k][s]; int ti = bi[k][s];
                            bd[k][s] = c ? vd : td;  bi[k][s] = c ? vi : ti;
                            vd       = c ? td : vd;  vi       = c ? ti : vi;
                        }
                    }
                }
            }
        }
    }

    unsigned long long lt = (1ull << lane) - 1ull;
    // ---- per node: T -> compact -> lex sort -> top-20 + suspect check ----
    // FULLY UNROLLED (k compile-time): dynamic bd[k][*] indexing caused scratch
    // spill in R5 (FETCH 2 GB, WRITE 869 MB) — keep every index static.
    #pragma unroll
    for (int k=0;k<4;k++){
        int node = n0g + w*4 + k;
        // T = 20th smallest of lane minima (exact upper bound on d20)
        float v = bd[k][0];
        #pragma unroll
        for (int K=2; K<=64; K<<=1){
            #pragma unroll
            for (int j=K>>1; j>0; j>>=1){
                float o = __shfl_xor(v, j);
                bool keepmin = (((lane & j) == 0) == ((lane & K) == 0));
                float mn = fminf(v,o), mx = fmaxf(v,o);
                v = keepmin ? mn : mx;
            }
        }
        float T = __shfl(v, 19);

        // compact retained values <= T into this wave's LDS buffer
        int cnt = 0;
        #pragma unroll
        for (int r=0;r<4;r++){
            bool take = (bd[k][r] <= T);
            unsigned long long m = __ballot(take);
            if (take){
                int off = cnt + (int)__popcll(m & lt);
                if (off < 64) sC[w*64 + off] = make_float2(bd[k][r], __int_as_float(bi[k][r]));
            }
            cnt += (int)__popcll(m);
        }
        int mm = cnt > 64 ? 64 : cnt;

        // lex bitonic-64 over compacted candidates
        float d; int idx;
        if (lane < mm){
            float2 e = sC[w*64 + lane];
            d = e.x; idx = __float_as_int(e.y);
        } else { d = BIG; idx = 0x7f000000 + lane; }
        #pragma unroll
        for (int K=2; K<=64; K<<=1){
            #pragma unroll
            for (int j=K>>1; j>0; j>>=1){
                float od = __shfl_xor(d, j);
                int   oi = __shfl_xor(idx, j);
                bool pless = (od < d) || (od == d && oi < idx);
                bool keepmin = (((lane & j) == 0) == ((lane & K) == 0));
                if (pless == keepmin){ d = od; idx = oi; }
            }
        }
        float T20 = __shfl(d, 19);

        // suspect: some lane's discards (all >= bd[k][3]) could rank within top-20
        bool susp = (bd[k][3] <= T20) || (cnt > 64);
        unsigned long long sm = __ballot(susp);
        if (sm){
            if (lane == 0){
                int slot = atomicAdd(sus_cnt, 1);
                sus_id[slot] = node;
            }
        }
        if (lane < KNN) nbr[(size_t)node*KNN + lane] = idx;
    }
}

// ---------------- fixup: exact top-8/lane + pop-merge for suspect nodes (R1-proven) ----------------
__global__ __launch_bounds__(64) void fixup_kernel(const float4* __restrict__ pos4,
                                                   const int* __restrict__ sus_cnt,
                                                   const int* __restrict__ sus_id,
                                                   int* __restrict__ nbr){
    int lane = threadIdx.x;
    int nsus = sus_cnt[0];
    for (int s = blockIdx.x; s < nsus; s += FIXG){
        int node = sus_id[s];
        int b = node >> 13;
        int i = node & (NB-1);
        const float4* __restrict__ P = pos4 + b*NB;
        float4 pi = P[i];
        float pwv = pi.w;
        float n2x = -2.0f*pi.x, n2y = -2.0f*pi.y, n2z = -2.0f*pi.z;

        float bd[8]; int bi8[8];
        #pragma unroll
        for (int r=0;r<8;r++){ bd[r] = BIG; bi8[r] = 0x7fffffff; }
        for (int tk=0; tk<128; ++tk){
            int j = (tk<<6) + lane;
            float4 q = P[j];
            float d2 = fmaf(n2x,q.x, fmaf(n2y,q.y, fmaf(n2z,q.z, pwv+q.w)));
            if (j == i) d2 = BIG;
            if (d2 < bd[7]){
                float vd = d2; int vi = j;
                #pragma unroll
                for (int r=0;r<8;r++){
                    bool c = vd < bd[r];
                    float td = bd[r]; int ti = bi8[r];
                    bd[r] = c ? vd : td;  bi8[r] = c ? vi : ti;
                    vd    = c ? td : vd;  vi    = c ? ti : vi;
                }
            }
        }
        int* outp = nbr + (size_t)node*KNN;
        for (int r=0; r<KNN; r++){
            float d = bd[0]; int ii = bi8[0];
            #pragma unroll
            for (int st=1; st<64; st<<=1){
                float od = __shfl_xor(d, st);
                int   oi = __shfl_xor(ii, st);
                if (od < d || (od == d && oi < ii)){ d = od; ii = oi; }
            }
            if (lane == 0) outp[r] = ii;
            if (bd[0] == d && bi8[0] == ii){
                #pragma unroll
                for (int st=0;st<7;st++){ bd[st]=bd[st+1]; bi8[st]=bi8[st+1]; }
                bd[7] = BIG; bi8[7] = 0x7fffffff;
            }
        }
    }
}

// ---------------- edge MLP (collapsed), 2 edges/thread, LDS weights ----------------
// ebuf: logit[NE], smsg[NE], ux[NE], uy[NE], uz[NE]
__global__ __launch_bounds__(256) void edge_kernel(const float4* __restrict__ pos4,
        const float4* __restrict__ vel4,
        const int* __restrict__ nbr,
        const float* __restrict__ pack,
        const float* __restrict__ be2,
        float* __restrict__ ebuf){
    __shared__ float4 sP[384];   // 6 KB: 3 float4 per h
    int tid = threadIdx.x;
    #pragma unroll
    for (int k=tid; k<384; k+=256) sP[k] = ((const float4*)pack)[k];
    __syncthreads();

    bool bb = (blockIdx.x >= 320);     // NE/2 = 163840 = 320*512, block-uniform batch
    int e1 = blockIdx.x*512 + tid;
    int e2 = e1 + 256;

    int i1 = e1 / KNN;
    int i2 = e2 / KNN;
    int base1 = (i1 >> 13)*NB;
    int base2 = (i2 >> 13)*NB;
    int s1 = nbr[e1], s2 = nbr[e2];
    float4 ps1 = pos4[base1 + s1], pt1 = pos4[i1];
    float4 vs1 = vel4[base1 + s1], vt1 = vel4[i1];
    float4 ps2 = pos4[base2 + s2], pt2 = pos4[i2];
    float4 vs2 = vel4[base2 + s2], vt2 = vel4[i2];

    float rx1 = ps1.x-pt1.x, ry1 = ps1.y-pt1.y, rz1 = ps1.z-pt1.z;
    float r21 = rx1*rx1 + ry1*ry1 + rz1*rz1;
    float vv1 = vs1.x*vt1.x + vs1.y*vt1.y + vs1.z*vt1.z;
    float vsr1= vs1.x*rx1 + vs1.y*ry1 + vs1.z*rz1;
    float vtr1= vt1.x*rx1 + vt1.y*ry1 + vt1.z*rz1;
    float mfs1= vs1.w, mft1 = vt1.w;

    float rx2 = ps2.x-pt2.x, ry2 = ps2.y-pt2.y, rz2 = ps2.z-pt2.z;
    float r22 = rx2*rx2 + ry2*ry2 + rz2*rz2;
    float vv2 = vs2.x*vt2.x + vs2.y*vt2.y + vs2.z*vt2.z;
    float vsr2= vs2.x*rx2 + vs2.y*ry2 + vs2.z*rz2;
    float vtr2= vt2.x*rx2 + vt2.y*ry2 + vt2.z*rz2;
    float mfs2= vs2.w, mft2 = vt2.w;

    float a0 = be2[0], a1 = be2[1], a2 = be2[2], a3 = be2[3];
    float b0 = a0, b1 = a1, b2 = a2, b3 = a3;
    #pragma unroll 4
    for (int h=0; h<128; h++){
        float4 A  = sP[h*3];
        float4 Bv = sP[h*3+1];
        float4 C  = sP[h*3+2];
        float base = bb ? A.y : A.x;
        float x1 = base + mfs1*A.z + mft1*A.w + r21*Bv.x + vv1*Bv.y + vsr1*Bv.z + vtr1*Bv.w;
        float x2 = base + mfs2*A.z + mft2*A.w + r22*Bv.x + vv2*Bv.y + vsr2*Bv.z + vtr2*Bv.w;
        float g1 = gelu_f(x1);
        float g2 = gelu_f(x2);
        a0 += g1*C.x; a1 += g1*C.y; a2 += g1*C.z; a3 += g1*C.w;
        b0 += g2*C.x; b1 += g2*C.y; b2 += g2*C.z; b3 += g2*C.w;
    }
    ebuf[e1]        = a0;
    ebuf[NE + e1]   = a1;
    ebuf[2*NE + e1] = a2*rx1 + a3*vs1.x;
    ebuf[3*NE + e1] = a2*ry1 + a3*vs1.y;
    ebuf[4*NE + e1] = a2*rz1 + a3*vs1.z;
    ebuf[e2]        = b0;
    ebuf[NE + e2]   = b1;
    ebuf[2*NE + e2] = b2*rx2 + b3*vs2.x;
    ebuf[3*NE + e2] = b2*ry2 + b3*vs2.y;
    ebuf[4*NE + e2] = b2*rz2 + b3*vs2.z;
}

// ---------------- node: softmax + aggregate + node MLP + output, wave per node ----------------
__global__ __launch_bounds__(256) void node_kernel(const float* __restrict__ z,
        const float4* __restrict__ vel4,
        const float* __restrict__ consts,
        const float* __restrict__ Wn1,
        const float* __restrict__ Wn2,
        const float* __restrict__ bn2,
        const float* __restrict__ alpha_p,
        const float* __restrict__ beta_p,
        const float* __restrict__ ebuf,
        float* __restrict__ out){
    int g = blockIdx.x*4 + (threadIdx.x>>6);
    int lane = threadIdx.x & 63;
    int b = g >> 13;

    float lg = -BIG, sm = 0.f, ux = 0.f, uy = 0.f, uz = 0.f;
    if (lane < KNN){
        size_t e = (size_t)g*KNN + lane;
        lg = ebuf[e]; sm = ebuf[NE+e]; ux = ebuf[2*NE+e]; uy = ebuf[3*NE+e]; uz = ebuf[4*NE+e];
    }
    float mx = wave_max(lg);
    float a = (lane < KNN) ? __expf(lg - mx) : 0.0f;
    float denom = wave_sum(a);
    float wv = a / denom;
    float sagg = wave_sum(wv*sm);
    float vax  = wave_sum(wv*ux);
    float vay  = wave_sum(wv*uy);
    float vaz  = wave_sum(wv*uz);

    float mf = vel4[g].w;
    float x = consts[512 + b*64 + lane] + mf*consts[640+lane] + sagg*Wn1[36*64+lane];
    float y = gelu_f(x)*Wn2[lane];
    float sout = wave_sum(y) + bn2[0];

    if (lane < 7){
        float alpha = alpha_p[0], beta = beta_p[0];
        float zl = z[(size_t)g*7 + lane];
        float r;
        if      (lane==0) r = zl + alpha*vax;
        else if (lane==1) r = zl + alpha*vay;
        else if (lane==2) r = zl + alpha*vaz;
        else if (lane==3) r = beta*vax;
        else if (lane==4) r = beta*vay;
        else if (lane==5) r = beta*vaz;
        else              r = sout;
        out[(size_t)g*7 + lane] = zl + r;
    }
}

extern "C" void kernel_launch(void* const* d_in, const int* in_sizes, int n_in,
                              void* d_out, int out_size, void* d_ws, size_t ws_size,
                              hipStream_t stream) {
    const float* z    = (const float*)d_in[0];
    const float* t    = (const float*)d_in[1];
    const float* cond = (const float*)d_in[2];
    const float* Wc1  = (const float*)d_in[4];
    const float* bc1  = (const float*)d_in[5];
    const float* Wc2  = (const float*)d_in[6];
    const float* bc2  = (const float*)d_in[7];
    const float* Wc3  = (const float*)d_in[8];
    const float* bc3  = (const float*)d_in[9];
    const float* We1  = (const float*)d_in[10];
    const float* be1  = (const float*)d_in[11];
    const float* We2  = (const float*)d_in[12];
    const float* be2  = (const float*)d_in[13];
    const float* Wn1  = (const float*)d_in[14];
    const float* bn1  = (const float*)d_in[15];
    const float* Wn2  = (const float*)d_in[16];
    const float* bn2  = (const float*)d_in[17];
    const float* alp  = (const float*)d_in[18];
    const float* bet  = (const float*)d_in[19];
    float* out = (float*)d_out;

    char* ws = (char*)d_ws;
    float4* pos4   = (float4*)(ws);                      // 262144 B
    float4* vel4   = (float4*)(ws + 262144);             // 262144 B
    float*  consts = (float*)(ws + 524288);              // 4096 B
    float*  pack   = (float*)(ws + 528384);              // 6144 B
    int*    nbr    = (int*)(ws + 534528);                // 1310720 B
    int*    sus_c  = (int*)(ws + 1845248);               // 256 B
    int*    sus_id = (int*)(ws + 1845504);               // 65536 B
    float*  ebuf   = (float*)(ws + 1911040);             // 6553600 B

    prep_kernel<<<dim3(BN/256), dim3(256), 0, stream>>>(z, pos4, vel4, sus_c);
    cond_kernel<<<dim3(BATCH), dim3(256), 0, stream>>>(t, cond, Wc1, bc1, Wc2, bc2,
                                                       Wc3, bc3, We1, be1, We2, Wn1, bn1,
                                                       consts, pack);
    knn_kernel<<<dim3(BN/32), dim3(512), 0, stream>>>(pos4, nbr, sus_c, sus_id);
    fixup_kernel<<<dim3(FIXG), dim3(64), 0, stream>>>(pos4, sus_c, sus_id, nbr);
    edge_kernel<<<dim3(NE/512), dim3(256), 0, stream>>>(pos4, vel4, nbr, pack, be2, ebuf);
    node_kernel<<<dim3(BN/4), dim3(256), 0, stream>>>(z, vel4, consts, Wn1, Wn2, bn2,
                                                      alp, bet, ebuf, out);
}

// Round 7
// 209.207 us; speedup vs baseline: 6.5898x; 1.4510x over previous
//
#include <hip/hip_runtime.h>
#include <math.h>

#define NB 8192
#define BATCH 2
#define KNN 20
#define BN (BATCH*NB)
#define NE (BN*KNN)        // 327680 edges
#define GT 16              // tiles per staged group (16 KB)
#define NG 8               // groups per pass
#define BIG 3.0e38f

__device__ __forceinline__ float gelu_f(float x){
    float x3 = x*x*x;
    float a = 0.7978845608028654f*(x + 0.044715f*x3);
    float e2 = __expf(2.0f*a);
    float th = 1.0f - __fdividef(2.0f, e2+1.0f);
    return 0.5f*x*(1.0f+th);
}

// ---------------- K1: prep (all 64 blocks) + cond MLP (blocks 0,1) ----------------
// consts floats: C[2][128]@0, S1[128]@256, S2[128]@384, D[2][64]@512, T1[64]@640
// pack per h (128): {C0,C1,S1,S2, W72,W73,W74,W75, V0,V1,V2,V3} = 12 floats
__global__ __launch_bounds__(256) void prepcond_kernel(const float* __restrict__ z,
        const float* __restrict__ t,
        const float* __restrict__ conditioning,
        const float* __restrict__ Wc1, const float* __restrict__ bc1,
        const float* __restrict__ Wc2, const float* __restrict__ bc2,
        const float* __restrict__ Wc3, const float* __restrict__ bc3,
        const float* __restrict__ We1, const float* __restrict__ be1,
        const float* __restrict__ We2,
        const float* __restrict__ Wn1, const float* __restrict__ bn1,
        float4* __restrict__ pos4, float4* __restrict__ vel4,
        float* __restrict__ consts, float* __restrict__ pack){
    int tid = threadIdx.x;
    int g = blockIdx.x*256 + tid;
    const float* zp = z + (size_t)g*7;
    float x = zp[0], y = zp[1], zz = zp[2];
    float r2 = x*x + y*y + zz*zz;
    pos4[g] = make_float4(x, y, zz, r2);
    vel4[g] = make_float4(zp[3], zp[4], zp[5], zp[6]);

    if (blockIdx.x >= BATCH) return;
    int b = blockIdx.x;
    __shared__ float ci[36];
    __shared__ float h1[144];
    __shared__ float h2[144];
    __shared__ float cnd[36];
    float tv = t[b];
    if (tid < 16){
        float f = expf(-9.210340371976184f * (float)tid / 15.0f);
        float a = tv*f;
        ci[tid]    = sinf(a);
        ci[16+tid] = cosf(a);
    }
    if (tid < 4) ci[32+tid] = conditioning[b*4+tid];
    __syncthreads();
    if (tid < 144){
        float acc = bc1[tid];
        #pragma unroll
        for (int c=0;c<36;c++) acc += ci[c]*Wc1[c*144+tid];
        h1[tid] = gelu_f(acc);
    }
    __syncthreads();
    if (tid < 144){
        float acc = bc2[tid];
        #pragma unroll 36
        for (int c=0;c<144;c++) acc += h1[c]*Wc2[c*144+tid];
        h2[tid] = gelu_f(acc);
    }
    __syncthreads();
    if (tid < 36){
        float acc = bc3[tid];
        #pragma unroll 36
        for (int c=0;c<144;c++) acc += h2[c]*Wc3[c*36+tid];
        cnd[tid] = acc;
    }
    __syncthreads();
    if (tid < 128){
        float accC = be1[tid], s1 = 0.f, s2 = 0.f;
        #pragma unroll
        for (int c=0;c<36;c++){
            float w1 = We1[c*128+tid];
            float w2 = We1[(36+c)*128+tid];
            accC += cnd[c]*(w1+w2);
            s1 += w1; s2 += w2;
        }
        consts[b*128+tid] = accC;
        pack[tid*12 + b] = accC;
        if (b==0){
            consts[256+tid] = s1; consts[384+tid] = s2;
            pack[tid*12+2] = s1;
            pack[tid*12+3] = s2;
            pack[tid*12+4] = We1[72*128+tid];
            pack[tid*12+5] = We1[73*128+tid];
            pack[tid*12+6] = We1[74*128+tid];
            pack[tid*12+7] = We1[75*128+tid];
            pack[tid*12+8]  = We2[tid*4+0];
            pack[tid*12+9]  = We2[tid*4+1];
            pack[tid*12+10] = We2[tid*4+2];
            pack[tid*12+11] = We2[tid*4+3];
        }
    }
    if (tid < 64){
        float accD = bn1[tid], t1 = 0.f;
        #pragma unroll
        for (int c=0;c<36;c++){
            float w = Wn1[c*64+tid];
            accD += cnd[c]*w;
            t1 += w;
        }
        consts[512 + b*64 + tid] = accD;
        if (b==0) consts[640+tid] = t1;
    }
}

// ---------------- K2: fused KNN + select (R4-proven two-pass), 8 waves x 4 nodes ----------------
// Pass A: per-lane min -> bitonic-64 -> T = 20th smallest (exact upper bound on d20)
// Pass B: rescan from LDS, ballot-compact d2<=T into LDS cand, bitonic by (d2,idx), top-20
__global__ __launch_bounds__(512, 4) void knn_kernel(const float4* __restrict__ pos4,
                                                     int* __restrict__ nbr){
    __shared__ float4 sPos[GT*64];      // 16 KB
    __shared__ float2 sCand[32*64];     // 16 KB
    int tid = threadIdx.x;
    int w = tid >> 6, lane = tid & 63;
    int n0g = blockIdx.x * 32;
    int b = n0g >> 13;
    int n0 = n0g & (NB-1);
    const float4* __restrict__ P = pos4 + b*NB;

    int nw = n0 + w*4;
    float nx[4], ny[4], nz[4], pw[4], acc[4];
    #pragma unroll
    for (int k=0;k<4;k++){
        float4 p = P[nw+k];
        nx[k] = -2.0f*p.x; ny[k] = -2.0f*p.y; nz[k] = -2.0f*p.z; pw[k] = p.w;
        acc[k] = BIG;
    }
    int selfTile = n0 >> 6;            // all 32 block nodes share one tile
    int sl0 = (n0 & 63) + w*4;         // self lane for node k is sl0+k

    // ---- Pass A ----
    float4 pre0 = P[(w*2    )*64 + lane];
    float4 pre1 = P[(w*2 + 1)*64 + lane];
    for (int g=0; g<NG; ++g){
        __syncthreads();
        sPos[(w*2    )*64 + lane] = pre0;
        sPos[(w*2 + 1)*64 + lane] = pre1;
        if (g+1 < NG){
            pre0 = P[((g+1)*GT + w*2    )*64 + lane];
            pre1 = P[((g+1)*GT + w*2 + 1)*64 + lane];
        }
        __syncthreads();
        int tbase = g*GT;
        #pragma unroll
        for (int t=0;t<GT;t++){
            float4 q = sPos[t*64 + lane];
            if (tbase + t != selfTile){
                #pragma unroll
                for (int k=0;k<4;k++){
                    float d2 = fmaf(nx[k],q.x, fmaf(ny[k],q.y, fmaf(nz[k],q.z, pw[k]+q.w)));
                    acc[k] = fminf(acc[k], d2);
                }
            } else {
                #pragma unroll
                for (int k=0;k<4;k++){
                    float d2 = fmaf(nx[k],q.x, fmaf(ny[k],q.y, fmaf(nz[k],q.z, pw[k]+q.w)));
                    if (lane == sl0 + k) d2 = BIG;
                    acc[k] = fminf(acc[k], d2);
                }
            }
        }
    }

    // ---- T[k] = 20th smallest of 64 per-lane minima ----
    float T[4];
    #pragma unroll
    for (int k=0;k<4;k++){
        float v = acc[k];
        #pragma unroll
        for (int K=2; K<=64; K<<=1){
            #pragma unroll
            for (int j=K>>1; j>0; j>>=1){
                float o = __shfl_xor(v, j);
                bool keepmin = (((lane & j) == 0) == ((lane & K) == 0));
                float mn = fminf(v,o), mx = fmaxf(v,o);
                v = keepmin ? mn : mx;
            }
        }
        T[k] = __shfl(v, 19);
    }

    // ---- Pass B: collect into LDS ----
    int cnt[4];
    #pragma unroll
    for (int k=0;k<4;k++) cnt[k] = 0;
    unsigned long long lt = (1ull << lane) - 1ull;

    pre0 = P[(w*2    )*64 + lane];
    pre1 = P[(w*2 + 1)*64 + lane];
    for (int g=0; g<NG; ++g){
        __syncthreads();
        sPos[(w*2    )*64 + lane] = pre0;
        sPos[(w*2 + 1)*64 + lane] = pre1;
        if (g+1 < NG){
            pre0 = P[((g+1)*GT + w*2    )*64 + lane];
            pre1 = P[((g+1)*GT + w*2 + 1)*64 + lane];
        }
        __syncthreads();
        int tbase = g*GT;
        #pragma unroll 4
        for (int t=0;t<GT;t++){
            int tile = tbase + t;
            float4 q = sPos[t*64 + lane];
            int j = (tile<<6) + lane;
            bool selft = (tile == selfTile);
            #pragma unroll
            for (int k=0;k<4;k++){
                float d2 = fmaf(nx[k],q.x, fmaf(ny[k],q.y, fmaf(nz[k],q.z, pw[k]+q.w)));
                bool hit = (d2 <= T[k]);
                if (selft && (lane == sl0 + k)) hit = false;
                unsigned long long m = __ballot(hit);
                if (m){
                    if (hit){
                        int off = cnt[k] + (int)__popcll(m & lt);
                        if (off < 64)
                            sCand[(w*4+k)*64 + off] = make_float2(d2, __int_as_float(j));
                    }
                    cnt[k] += (int)__popcll(m);
                }
            }
        }
    }

    // ---- sort each node's candidates (same-wave data; no barrier needed) ----
    #pragma unroll
    for (int k=0;k<4;k++){
        int m = cnt[k]; if (m > 64) m = 64;
        float d; int idx;
        if (lane < m){
            float2 e = sCand[(w*4+k)*64 + lane];
            d = e.x; idx = __float_as_int(e.y);
        } else { d = BIG; idx = 0x7f000000 + lane; }
        #pragma unroll
        for (int K=2; K<=64; K<<=1){
            #pragma unroll
            for (int j=K>>1; j>0; j>>=1){
                float od = __shfl_xor(d, j);
                int   oi = __shfl_xor(idx, j);
                bool pless = (od < d) || (od == d && oi < idx);
                bool keepmin = (((lane & j) == 0) == ((lane & K) == 0));
                if (pless == keepmin){ d = od; idx = oi; }
            }
        }
        if (lane < KNN) nbr[(size_t)(n0g + w*4 + k)*KNN + lane] = idx;
    }
}

// ---------------- K3: fused edge MLP + softmax-aggregate + node MLP + output ----------------
// 1024 blocks x 320 threads; block owns 16 nodes = 320 edges exactly.
__global__ __launch_bounds__(320) void edgenode_kernel(const float4* __restrict__ pos4,
        const float4* __restrict__ vel4,
        const int* __restrict__ nbr,
        const float* __restrict__ pack,
        const float* __restrict__ consts,
        const float* __restrict__ Wn1,
        const float* __restrict__ Wn2,
        const float* __restrict__ be2,
        const float* __restrict__ bn2,
        const float* __restrict__ alpha_p,
        const float* __restrict__ beta_p,
        const float* __restrict__ z,
        float* __restrict__ out){
    __shared__ float4 sP[384];                       // 6 KB edge weights
    __shared__ float sLg[320], sSm[320], sUx[320], sUy[320], sUz[320];  // 6.25 KB
    __shared__ float sD[64], sT1[64], sW36[64], sWo[64];
    __shared__ float sMf[16];
    __shared__ float4 sAgg[16];                      // {vax,vay,vaz,sagg}
    __shared__ float sPart[320];

    int tid = threadIdx.x;
    bool bb = (blockIdx.x >= 512);                   // batch block-uniform
    for (int k=tid; k<384; k+=320) sP[k] = ((const float4*)pack)[k];
    if (tid < 64){
        sD[tid]   = consts[512 + (bb?64:0) + tid];
        sT1[tid]  = consts[640+tid];
        sW36[tid] = Wn1[36*64+tid];
        sWo[tid]  = Wn2[tid];
    }

    int e = blockIdx.x*320 + tid;
    int i = e / KNN;                   // global tgt node
    int ln = tid / KNN;                // local node 0..15
    int r  = tid - ln*KNN;             // edge rank 0..19
    int bbase = bb ? NB : 0;
    int s = nbr[e];
    float4 ps = pos4[bbase + s], pt = pos4[i];
    float4 vs = vel4[bbase + s], vt = vel4[i];
    if (r == 0) sMf[ln] = vt.w;

    float rx = ps.x - pt.x, ry = ps.y - pt.y, rz = ps.z - pt.z;
    float r2  = rx*rx + ry*ry + rz*rz;
    float vv  = vs.x*vt.x + vs.y*vt.y + vs.z*vt.z;
    float vsr = vs.x*rx + vs.y*ry + vs.z*rz;
    float vtr = vt.x*rx + vt.y*ry + vt.z*rz;
    float mfs = vs.w, mft = vt.w;
    __syncthreads();   // sP ready

    float a0 = be2[0], a1 = be2[1], a2 = be2[2], a3 = be2[3];
    #pragma unroll 4
    for (int h=0; h<128; h++){
        float4 A  = sP[h*3];
        float4 Bv = sP[h*3+1];
        float4 C  = sP[h*3+2];
        float base = bb ? A.y : A.x;
        float x = base + mfs*A.z + mft*A.w + r2*Bv.x + vv*Bv.y + vsr*Bv.z + vtr*Bv.w;
        float gx = gelu_f(x);
        a0 += gx*C.x; a1 += gx*C.y; a2 += gx*C.z; a3 += gx*C.w;
    }
    sLg[tid] = a0;
    sSm[tid] = a1;
    sUx[tid] = a2*rx + a3*vs.x;
    sUy[tid] = a2*ry + a3*vs.y;
    sUz[tid] = a2*rz + a3*vs.z;
    __syncthreads();

    // per-node softmax + aggregation (16 serial lanes)
    if (tid < 16){
        int base = tid*KNN;
        float m = -BIG;
        #pragma unroll
        for (int q=0;q<KNN;q++) m = fmaxf(m, sLg[base+q]);
        float den=0.f, wx=0.f, wy=0.f, wz=0.f, wsm=0.f;
        #pragma unroll
        for (int q=0;q<KNN;q++){
            float a = __expf(sLg[base+q]-m);
            den += a;
            wsm += a*sSm[base+q];
            wx  += a*sUx[base+q];
            wy  += a*sUy[base+q];
            wz  += a*sUz[base+q];
        }
        float inv = __fdividef(1.0f, den);
        sAgg[tid] = make_float4(wx*inv, wy*inv, wz*inv, wsm*inv);
    }
    __syncthreads();

    // node MLP partials: 20 threads per node, h = r, r+20, r+40, (r+60)
    {
        float mf = sMf[ln];
        float sg = sAgg[ln].w;
        float part = 0.f;
        #pragma unroll
        for (int h=r; h<64; h+=KNN){
            float x = sD[h] + mf*sT1[h] + sg*sW36[h];
            part += gelu_f(x)*sWo[h];
        }
        sPart[tid] = part;
    }
    __syncthreads();

    if (tid < 16){
        float sout = bn2[0];
        #pragma unroll
        for (int q=0;q<KNN;q++) sout += sPart[tid*KNN+q];
        int node = blockIdx.x*16 + tid;
        float alpha = alpha_p[0], beta = beta_p[0];
        float4 ag = sAgg[tid];
        const float* zp = z + (size_t)node*7;
        float* op = out + (size_t)node*7;
        op[0] = zp[0]*2.0f + alpha*ag.x;
        op[1] = zp[1]*2.0f + alpha*ag.y;
        op[2] = zp[2]*2.0f + alpha*ag.z;
        op[3] = zp[3] + beta*ag.x;
        op[4] = zp[4] + beta*ag.y;
        op[5] = zp[5] + beta*ag.z;
        op[6] = zp[6] + sout;
    }
}

extern "C" void kernel_launch(void* const* d_in, const int* in_sizes, int n_in,
                              void* d_out, int out_size, void* d_ws, size_t ws_size,
                              hipStream_t stream) {
    const float* z    = (const float*)d_in[0];
    const float* t    = (const float*)d_in[1];
    const float* cond = (const float*)d_in[2];
    const float* Wc1  = (const float*)d_in[4];
    const float* bc1  = (const float*)d_in[5];
    const float* Wc2  = (const float*)d_in[6];
    const float* bc2  = (const float*)d_in[7];
    const float* Wc3  = (const float*)d_in[8];
    const float* bc3  = (const float*)d_in[9];
    const float* We1  = (const float*)d_in[10];
    const float* be1  = (const float*)d_in[11];
    const float* We2  = (const float*)d_in[12];
    const float* be2  = (const float*)d_in[13];
    const float* Wn1  = (const float*)d_in[14];
    const float* bn1  = (const float*)d_in[15];
    const float* Wn2  = (const float*)d_in[16];
    const float* bn2  = (const float*)d_in[17];
    const float* alp  = (const float*)d_in[18];
    const float* bet  = (const float*)d_in[19];
    float* out = (float*)d_out;

    char* ws = (char*)d_ws;
    float4* pos4   = (float4*)(ws);                      // 262144 B
    float4* vel4   = (float4*)(ws + 262144);             // 262144 B
    float*  consts = (float*)(ws + 524288);              // 4096 B
    float*  pack   = (float*)(ws + 528384);              // 6144 B
    int*    nbr    = (int*)(ws + 534528);                // 1310720 B

    prepcond_kernel<<<dim3(BN/256), dim3(256), 0, stream>>>(z, t, cond,
        Wc1, bc1, Wc2, bc2, Wc3, bc3, We1, be1, We2, Wn1, bn1,
        pos4, vel4, consts, pack);
    knn_kernel<<<dim3(BN/32), dim3(512), 0, stream>>>(pos4, nbr);
    edgenode_kernel<<<dim3(BN/16), dim3(320), 0, stream>>>(pos4, vel4, nbr, pack, consts,
        Wn1, Wn2, be2, bn2, alp, bet, z, out);
}